// Round 1
// baseline (233.090 us; speedup 1.0000x reference)
//
#include <hip/hip_runtime.h>

// EMA chunked scan + inverse-gather broadcast for DeChunkLayer.
// x: (1, 16384, 1024) f32, p_selected: (16384,) f32, b: (1, 32768) i32
// out: (1, 32768, 1024) f32
//
// z_t = (1-p_t) z_{t-1} + p_t x_t  (p clipped to [1e-4, 1-1e-4])
// out[f] = z[cumsum(b)[f]-1]  ==  out[f] = z[t] for f in [pos[t], pos[t+1])

#define DCH 1024
#define L_COMP 16384
#define L_FULL 32768
#define CHUNK 64
#define NCHUNK (L_COMP / CHUNK) // 256
#define EPSV 1e-4f

__device__ __forceinline__ float clipp(float p) {
    p = fmaxf(p, EPSV);
    p = fminf(p, 1.0f - EPSV);
    return p;
}

// ---- Kernel 0: boundary mask -> pos[] (positions of the 16384 ones, plus sentinel L_FULL)
__global__ __launch_bounds__(1024) void pos_kernel(const int* __restrict__ b, int* __restrict__ pos) {
    __shared__ int sums[1024];
    const int tid = threadIdx.x;
    int vals[32];
    const int4* b4 = reinterpret_cast<const int4*>(b) + tid * 8;
#pragma unroll
    for (int j = 0; j < 8; ++j) {
        int4 v = b4[j];
        vals[4 * j + 0] = v.x; vals[4 * j + 1] = v.y;
        vals[4 * j + 2] = v.z; vals[4 * j + 3] = v.w;
    }
    int s = 0;
#pragma unroll
    for (int k = 0; k < 32; ++k) s += vals[k];
    sums[tid] = s;
    __syncthreads();
    // Hillis-Steele inclusive scan over 1024 per-thread sums
    for (int off = 1; off < 1024; off <<= 1) {
        int v = sums[tid];
        int add = (tid >= off) ? sums[tid - off] : 0;
        __syncthreads();
        sums[tid] = v + add;
        __syncthreads();
    }
    int idx = (tid == 0) ? 0 : sums[tid - 1];
#pragma unroll
    for (int k = 0; k < 32; ++k) {
        if (vals[k]) pos[idx++] = tid * 32 + k;
    }
    if (tid == 0) pos[L_COMP] = L_FULL;
}

// ---- Kernel A: per-chunk local scan (zero init) -> B_c[d] and chunk decay product A_c
__global__ __launch_bounds__(256) void chunk_kernel(const float* __restrict__ x, const float* __restrict__ p,
                                                    float* __restrict__ Bbuf, float* __restrict__ Abuf) {
    const int c = blockIdx.x;
    const int tid = threadIdx.x;
    const float4* x4 = reinterpret_cast<const float4*>(x) + (size_t)c * CHUNK * (DCH / 4) + tid;
    float4 h = make_float4(0.f, 0.f, 0.f, 0.f);
    float aprod = 1.0f;
    const int base = c * CHUNK;
#pragma unroll 8
    for (int i = 0; i < CHUNK; ++i) {
        float pv = clipp(p[base + i]);   // uniform -> scalar load
        float a = 1.0f - pv;
        float4 xv = x4[i * (DCH / 4)];
        h.x = fmaf(a, h.x, pv * xv.x);
        h.y = fmaf(a, h.y, pv * xv.y);
        h.z = fmaf(a, h.z, pv * xv.z);
        h.w = fmaf(a, h.w, pv * xv.w);
        aprod *= a;
    }
    reinterpret_cast<float4*>(Bbuf)[c * (DCH / 4) + tid] = h;
    if (tid == 0) Abuf[c] = aprod;
}

// ---- Kernel B: sequential inter-chunk scan per channel; Hbuf[c][d] = state BEFORE chunk c
#define BATCHB 32
__global__ __launch_bounds__(64) void interchunk_kernel(const float* __restrict__ Bbuf,
                                                        const float* __restrict__ Abuf,
                                                        float* __restrict__ Hbuf) {
    const int ch = blockIdx.x * 64 + threadIdx.x; // 16 blocks x 64 = 1024 channels
    float h = 0.f;
    for (int cb = 0; cb < NCHUNK; cb += BATCHB) {
        float bv[BATCHB];
        float av[BATCHB];
#pragma unroll
        for (int j = 0; j < BATCHB; ++j) {
            bv[j] = Bbuf[(cb + j) * DCH + ch];
            av[j] = Abuf[cb + j]; // uniform -> SGPR
        }
#pragma unroll
        for (int j = 0; j < BATCHB; ++j) {
            Hbuf[(cb + j) * DCH + ch] = h;
            h = fmaf(av[j], h, bv[j]);
        }
    }
}

// ---- Kernel C: re-scan chunk with true initial state, broadcast-write each row to its
//      output range [pos[t], pos[t+1]) (uniform trip count across the block).
__global__ __launch_bounds__(256) void final_kernel(const float* __restrict__ x, const float* __restrict__ p,
                                                    const float* __restrict__ Hbuf, const int* __restrict__ pos,
                                                    float* __restrict__ out) {
    const int c = blockIdx.x;
    const int tid = threadIdx.x;
    const float4* x4 = reinterpret_cast<const float4*>(x) + (size_t)c * CHUNK * (DCH / 4) + tid;
    float4* out4 = reinterpret_cast<float4*>(out) + tid;
    float4 h = reinterpret_cast<const float4*>(Hbuf)[c * (DCH / 4) + tid];
    const int base = c * CHUNK;
    int f0 = pos[base];
    for (int i = 0; i < CHUNK; ++i) {
        float pv = clipp(p[base + i]);
        float a = 1.0f - pv;
        float4 xv = x4[i * (DCH / 4)];
        h.x = fmaf(a, h.x, pv * xv.x);
        h.y = fmaf(a, h.y, pv * xv.y);
        h.z = fmaf(a, h.z, pv * xv.z);
        h.w = fmaf(a, h.w, pv * xv.w);
        int f1 = pos[base + i + 1]; // uniform -> scalar load
        for (int f = f0; f < f1; ++f) {
            out4[(size_t)f * (DCH / 4)] = h;
        }
        f0 = f1;
    }
}

extern "C" void kernel_launch(void* const* d_in, const int* in_sizes, int n_in,
                              void* d_out, int out_size, void* d_ws, size_t ws_size,
                              hipStream_t stream) {
    const float* x = (const float*)d_in[0];
    const float* p = (const float*)d_in[1];
    const int* b = (const int*)d_in[2];
    float* out = (float*)d_out;

    char* ws = (char*)d_ws;
    float* Abuf = (float*)ws;                       // NCHUNK floats (1 KiB)
    int* pos = (int*)(ws + 4096);                   // (L_COMP+1) ints (~64 KiB)
    float* Bbuf = (float*)(ws + 4096 + 69632);      // NCHUNK*DCH floats (1 MiB), 16B aligned
    float* Hbuf = Bbuf + (size_t)NCHUNK * DCH;      // NCHUNK*DCH floats (1 MiB)

    pos_kernel<<<1, 1024, 0, stream>>>(b, pos);
    chunk_kernel<<<NCHUNK, 256, 0, stream>>>(x, p, Bbuf, Abuf);
    interchunk_kernel<<<16, 64, 0, stream>>>(Bbuf, Abuf, Hbuf);
    final_kernel<<<NCHUNK, 256, 0, stream>>>(x, p, Hbuf, pos, out);
}